// Round 2
// baseline (997.124 us; speedup 1.0000x reference)
//
#include <hip/hip_runtime.h>
#include <hip/hip_bf16.h>
#include <stdint.h>

// GraphConv (GCN layer), N=100000 nodes, E=1.6M edges, D_in=D_out=256, f32 in/out.
// Pipeline:
//   1. degree counts (int atomics)
//   2. pre[n]=rsqrt(max(outdeg,1)), post[n]=rsqrt(max(indeg,1))
//   3. exclusive scan of in-degree -> CSR row_ptr (+cursor copy)
//   4. CSR fill: bucket src ids by dst via atomic cursor
//   5. aggregation: one wave per dst node, gather feat[src]*pre[src], f32 acc,
//      write agg row as bf16
//   6. GEMM: agg_bf16 @ W_bf16 via mfma_f32_16x16x32_bf16, epilogue *post + bias

using short8  = __attribute__((ext_vector_type(8))) short;
using floatx4 = __attribute__((ext_vector_type(4))) float;

static __device__ __forceinline__ unsigned short f32_to_bf16(float f) {
    unsigned int u = __float_as_uint(f);
    u += 0x7FFFu + ((u >> 16) & 1u);   // round-to-nearest-even
    return (unsigned short)(u >> 16);
}

__global__ void k_deg(const int* __restrict__ src, const int* __restrict__ dst,
                      int E, int* __restrict__ outc, int* __restrict__ inc) {
    int i = blockIdx.x * blockDim.x + threadIdx.x;
    int stride = gridDim.x * blockDim.x;
    for (; i < E; i += stride) {
        atomicAdd(&outc[src[i]], 1);
        atomicAdd(&inc[dst[i]], 1);
    }
}

__global__ void k_prepost(const int* __restrict__ outc, const int* __restrict__ inc,
                          int N, float* __restrict__ pre, float* __restrict__ post) {
    int i = blockIdx.x * blockDim.x + threadIdx.x;
    if (i < N) {
        pre[i]  = rsqrtf((float)max(outc[i], 1));
        post[i] = rsqrtf((float)max(inc[i], 1));
    }
}

// single-block exclusive scan of inc[0..N) -> row_ptr[0..N], cursor copy
__global__ void k_scan(const int* __restrict__ inc, int N,
                       int* __restrict__ row_ptr, int* __restrict__ cursor) {
    __shared__ int ss[1024];
    int t = threadIdx.x;
    int chunk = (N + 1023) >> 10;
    int b = t * chunk;
    int e = min(b + chunk, N);
    int s = 0;
    for (int i = b; i < e; ++i) s += inc[i];
    ss[t] = s;
    __syncthreads();
    for (int off = 1; off < 1024; off <<= 1) {
        int v = (t >= off) ? ss[t - off] : 0;
        __syncthreads();
        ss[t] += v;
        __syncthreads();
    }
    int run = ss[t] - s;   // exclusive prefix for this chunk
    for (int i = b; i < e; ++i) {
        row_ptr[i] = run;
        cursor[i] = run;
        run += inc[i];
    }
    if (t == 1023) row_ptr[N] = run;   // == E
}

__global__ void k_fill(const int* __restrict__ src, const int* __restrict__ dst,
                       int E, int* __restrict__ cursor, int* __restrict__ eidx) {
    int i = blockIdx.x * blockDim.x + threadIdx.x;
    int stride = gridDim.x * blockDim.x;
    for (; i < E; i += stride) {
        int p = atomicAdd(&cursor[dst[i]], 1);
        eidx[p] = src[i];
    }
}

// WT[n*256+k] = bf16(W[k*256+n])
__global__ void k_wt(const float* __restrict__ W, unsigned short* __restrict__ WT) {
    int i = blockIdx.x * blockDim.x + threadIdx.x;   // 65536 threads
    int n = i >> 8, k = i & 255;
    WT[n * 256 + k] = f32_to_bf16(W[(size_t)k * 256 + n]);
}

// one wave per destination node; lane owns 4 consecutive f32 columns
__global__ void k_agg(const float* __restrict__ feat, const float* __restrict__ pre,
                      const int* __restrict__ row_ptr, const int* __restrict__ eidx,
                      int N, unsigned short* __restrict__ aggb) {
    int wave = blockIdx.x * (blockDim.x >> 6) + (threadIdx.x >> 6);
    if (wave >= N) return;
    int lane = threadIdx.x & 63;
    int s0 = row_ptr[wave], s1 = row_ptr[wave + 1];
    float a0 = 0.f, a1 = 0.f, a2 = 0.f, a3 = 0.f;
    float b0 = 0.f, b1 = 0.f, b2 = 0.f, b3 = 0.f;
    int e = s0;
    // 2-edge unroll: two independent gathers in flight
    for (; e + 1 < s1; e += 2) {
        int sA = eidx[e];
        int sB = eidx[e + 1];
        float pA = pre[sA];
        float pB = pre[sB];
        float4 vA = *(const float4*)(feat + (size_t)sA * 256 + lane * 4);
        float4 vB = *(const float4*)(feat + (size_t)sB * 256 + lane * 4);
        a0 = fmaf(vA.x, pA, a0);
        a1 = fmaf(vA.y, pA, a1);
        a2 = fmaf(vA.z, pA, a2);
        a3 = fmaf(vA.w, pA, a3);
        b0 = fmaf(vB.x, pB, b0);
        b1 = fmaf(vB.y, pB, b1);
        b2 = fmaf(vB.z, pB, b2);
        b3 = fmaf(vB.w, pB, b3);
    }
    if (e < s1) {
        int s = eidx[e];
        float p = pre[s];
        float4 v = *(const float4*)(feat + (size_t)s * 256 + lane * 4);
        a0 = fmaf(v.x, p, a0);
        a1 = fmaf(v.y, p, a1);
        a2 = fmaf(v.z, p, a2);
        a3 = fmaf(v.w, p, a3);
    }
    a0 += b0; a1 += b1; a2 += b2; a3 += b3;
    ushort4 u;
    u.x = f32_to_bf16(a0);
    u.y = f32_to_bf16(a1);
    u.z = f32_to_bf16(a2);
    u.w = f32_to_bf16(a3);
    *(ushort4*)(aggb + (size_t)wave * 256 + lane * 4) = u;
}

// per wave: 16 rows x 256 cols output tile. K=256 (8 mfma k-steps), N-tiles=16.
__global__ void __launch_bounds__(256)
k_gemm(const unsigned short* __restrict__ aggb, const unsigned short* __restrict__ WT,
       const float* __restrict__ post, const float* __restrict__ bias,
       int N, float* __restrict__ out) {
    int wave = blockIdx.x * 4 + (threadIdx.x >> 6);
    int m0 = wave * 16;
    if (m0 >= N) return;
    int lane = threadIdx.x & 63;
    int r = lane & 15;       // A row / B col within 16
    int g = lane >> 4;       // k-group 0..3

    floatx4 acc[16];
#pragma unroll
    for (int n = 0; n < 16; ++n) acc[n] = (floatx4){0.f, 0.f, 0.f, 0.f};

#pragma unroll
    for (int k = 0; k < 8; ++k) {
        short8 a = *(const short8*)(aggb + (size_t)(m0 + r) * 256 + k * 32 + g * 8);
#pragma unroll
        for (int n = 0; n < 16; ++n) {
            short8 b = *(const short8*)(WT + (size_t)(n * 16 + r) * 256 + k * 32 + g * 8);
            acc[n] = __builtin_amdgcn_mfma_f32_16x16x32_bf16(a, b, acc[n], 0, 0, 0);
        }
    }

    float pr[4];
#pragma unroll
    for (int i = 0; i < 4; ++i) pr[i] = post[m0 + g * 4 + i];

#pragma unroll
    for (int n = 0; n < 16; ++n) {
        int c = n * 16 + r;
        float bs = bias[c];
#pragma unroll
        for (int i = 0; i < 4; ++i) {
            int row = m0 + g * 4 + i;
            out[(size_t)row * 256 + c] = acc[n][i] * pr[i] + bs;
        }
    }
}

extern "C" void kernel_launch(void* const* d_in, const int* in_sizes, int n_in,
                              void* d_out, int out_size, void* d_ws, size_t ws_size,
                              hipStream_t stream) {
    const float* feat = (const float*)d_in[0];
    const int*   src  = (const int*)d_in[1];
    const int*   dst  = (const int*)d_in[2];
    const float* W    = (const float*)d_in[3];
    const float* bias = (const float*)d_in[4];
    float* out = (float*)d_out;

    const int D = 256;
    int N = in_sizes[0] / D;   // 100000
    int E = in_sizes[1];       // 1600000

    // workspace layout (256B aligned chunks)
    char* ws = (char*)d_ws;
    size_t off = 0;
    auto alloc = [&](size_t bytes) -> void* {
        void* p = ws + off;
        off += (bytes + 255) & ~(size_t)255;
        return p;
    };
    int*            cnt     = (int*)alloc((size_t)2 * N * sizeof(int)); // outc|inc
    int*            outc    = cnt;
    int*            inc     = cnt + N;
    float*          pre     = (float*)alloc((size_t)N * sizeof(float));
    float*          post    = (float*)alloc((size_t)N * sizeof(float));
    int*            row_ptr = (int*)alloc((size_t)(N + 1) * sizeof(int));
    int*            cursor  = (int*)alloc((size_t)N * sizeof(int));
    int*            eidx    = (int*)alloc((size_t)E * sizeof(int));
    unsigned short* aggb    = (unsigned short*)alloc((size_t)N * D * sizeof(unsigned short));
    unsigned short* WT      = (unsigned short*)alloc((size_t)D * D * sizeof(unsigned short));
    (void)ws_size;

    hipMemsetAsync(cnt, 0, (size_t)2 * N * sizeof(int), stream);

    k_deg<<<1024, 256, 0, stream>>>(src, dst, E, outc, inc);
    k_prepost<<<(N + 255) / 256, 256, 0, stream>>>(outc, inc, N, pre, post);
    k_scan<<<1, 1024, 0, stream>>>(inc, N, row_ptr, cursor);
    k_fill<<<1024, 256, 0, stream>>>(src, dst, E, cursor, eidx);
    k_wt<<<(D * D) / 256, 256, 0, stream>>>(W, WT);
    k_agg<<<(N + 3) / 4, 256, 0, stream>>>(feat, pre, row_ptr, eidx, N, aggb);
    k_gemm<<<(N / 16 + 3) / 4, 256, 0, stream>>>(aggb, WT, post, bias, N, out);
}

// Round 3
// 680.505 us; speedup vs baseline: 1.4653x; 1.4653x over previous
//
#include <hip/hip_runtime.h>
#include <hip/hip_bf16.h>
#include <stdint.h>

// GraphConv (GCN layer), N=100000, E=1.6M, D=256, f32 in/out.
// Reordered pipeline (aggregation is linear, so project first):
//   1. k_deg: degree counts (int atomics)
//   2. k_off: CSR bucket offsets via per-block LDS scan + atomic base (order-free)
//   3. k_fill: bucket src ids by dst via atomic cursor
//   4. k_wt:  WT[n][k] = bf16(W[k][n])
//   5. k_hb:  h[n] = bf16(feat[n] * rsqrt(max(outdeg,1)))          [51.2 MB]
//   6. k_gemm: z = h @ W, bf16, IN-PLACE over h (block reads its own 16 rows
//              during the K-loop, writes them only in the epilogue)
//   7. k_agg: out[n] = rsqrt(max(indeg,1)) * sum_{src in-edges} z[src] + bias
//             (gathers 512B bf16 rows, f32 accum, writes final f32)

using short8  = __attribute__((ext_vector_type(8))) short;
using floatx4 = __attribute__((ext_vector_type(4))) float;

static __device__ __forceinline__ unsigned short f32_to_bf16(float f) {
    unsigned int u = __float_as_uint(f);
    u += 0x7FFFu + ((u >> 16) & 1u);   // round-to-nearest-even
    return (unsigned short)(u >> 16);
}
static __device__ __forceinline__ float bf2f(unsigned short u) {
    return __uint_as_float((unsigned int)u << 16);
}

__global__ void k_deg(const int* __restrict__ src, const int* __restrict__ dst,
                      int E, int* __restrict__ outc, int* __restrict__ inc) {
    int i = blockIdx.x * blockDim.x + threadIdx.x;
    int stride = gridDim.x * blockDim.x;
    for (; i < E; i += stride) {
        atomicAdd(&outc[src[i]], 1);
        atomicAdd(&inc[dst[i]], 1);
    }
}

// per-block exclusive scan + atomic global base -> start/cursor (bucket order
// across blocks is arbitrary; only start[n] / start[n]+deg[n] consistency matters)
__global__ void k_off(const int* __restrict__ inc, int N, int* __restrict__ total,
                      int* __restrict__ start, int* __restrict__ cursor) {
    __shared__ int ss[256];
    __shared__ int sbase;
    int t = threadIdx.x;
    int i = blockIdx.x * 256 + t;
    int d = (i < N) ? inc[i] : 0;
    int v = d;
    ss[t] = v;
    __syncthreads();
    for (int off = 1; off < 256; off <<= 1) {
        int u = (t >= off) ? ss[t - off] : 0;
        __syncthreads();
        v += u;
        ss[t] = v;
        __syncthreads();
    }
    if (t == 255) sbase = atomicAdd(total, v);   // v = block sum
    __syncthreads();
    if (i < N) {
        int b = sbase + (v - d);                 // exclusive prefix
        start[i] = b;
        cursor[i] = b;
    }
}

__global__ void k_fill(const int* __restrict__ src, const int* __restrict__ dst,
                       int E, int* __restrict__ cursor, int* __restrict__ eidx) {
    int i = blockIdx.x * blockDim.x + threadIdx.x;
    int stride = gridDim.x * blockDim.x;
    for (; i < E; i += stride) {
        int p = atomicAdd(&cursor[dst[i]], 1);
        eidx[p] = src[i];
    }
}

// WT[n*256+k] = bf16(W[k*256+n])
__global__ void k_wt(const float* __restrict__ W, unsigned short* __restrict__ WT) {
    int i = blockIdx.x * blockDim.x + threadIdx.x;   // 65536 threads
    int n = i >> 8, k = i & 255;
    WT[n * 256 + k] = f32_to_bf16(W[(size_t)k * 256 + n]);
}

// h[n][k] = bf16(feat[n][k] * rsqrt(max(outdeg,1))); one wave per row
__global__ void k_hb(const float* __restrict__ feat, const int* __restrict__ outc,
                     int N, unsigned short* __restrict__ h) {
    int node = blockIdx.x * 4 + (threadIdx.x >> 6);
    if (node >= N) return;
    int lane = threadIdx.x & 63;
    float p = rsqrtf((float)max(outc[node], 1));
    float4 v = *(const float4*)(feat + (size_t)node * 256 + lane * 4);
    ushort4 u;
    u.x = f32_to_bf16(v.x * p);
    u.y = f32_to_bf16(v.y * p);
    u.z = f32_to_bf16(v.z * p);
    u.w = f32_to_bf16(v.w * p);
    *(ushort4*)(h + (size_t)node * 256 + lane * 4) = u;
}

// z = h @ W (bf16 out), in-place over h. Per wave: 16 rows x 256 cols.
__global__ void __launch_bounds__(256)
k_gemm(unsigned short* h /* in: h, out: z */, const unsigned short* __restrict__ WT,
       int N) {
    int wave = blockIdx.x * 4 + (threadIdx.x >> 6);
    int m0 = wave * 16;
    if (m0 >= N) return;
    int lane = threadIdx.x & 63;
    int r = lane & 15;       // A row / B col within 16
    int g = lane >> 4;       // k-group 0..3

    floatx4 acc[16];
#pragma unroll
    for (int n = 0; n < 16; ++n) acc[n] = (floatx4){0.f, 0.f, 0.f, 0.f};

#pragma unroll
    for (int k = 0; k < 8; ++k) {
        short8 a = *(const short8*)(h + (size_t)(m0 + r) * 256 + k * 32 + g * 8);
#pragma unroll
        for (int n = 0; n < 16; ++n) {
            short8 b = *(const short8*)(WT + (size_t)(n * 16 + r) * 256 + k * 32 + g * 8);
            acc[n] = __builtin_amdgcn_mfma_f32_16x16x32_bf16(a, b, acc[n], 0, 0, 0);
        }
    }

    // epilogue: write z (bf16) over h rows; all reads of these rows are done
#pragma unroll
    for (int n = 0; n < 16; ++n) {
        int c = n * 16 + r;
#pragma unroll
        for (int i = 0; i < 4; ++i) {
            int row = m0 + g * 4 + i;
            h[(size_t)row * 256 + c] = f32_to_bf16(acc[n][i]);
        }
    }
}

// out[n] = rsqrt(max(deg,1)) * sum z[src] + bias; one wave per dst node
__global__ void k_agg(const unsigned short* __restrict__ z,
                      const int* __restrict__ start, const int* __restrict__ inc,
                      const int* __restrict__ eidx, const float* __restrict__ bias,
                      int N, float* __restrict__ out) {
    int node = blockIdx.x * 4 + (threadIdx.x >> 6);
    if (node >= N) return;
    int lane = threadIdx.x & 63;
    int deg = inc[node];
    const int* ep = eidx + start[node];

    float a0 = 0.f, a1 = 0.f, a2 = 0.f, a3 = 0.f;
    float b0 = 0.f, b1 = 0.f, b2 = 0.f, b3 = 0.f;
    float c0 = 0.f, c1 = 0.f, c2 = 0.f, c3 = 0.f;
    float d0 = 0.f, d1 = 0.f, d2 = 0.f, d3 = 0.f;
    int e = 0;
    for (; e + 3 < deg; e += 4) {
        int sA = ep[e], sB = ep[e + 1], sC = ep[e + 2], sD = ep[e + 3];
        ushort4 vA = *(const ushort4*)(z + (size_t)sA * 256 + lane * 4);
        ushort4 vB = *(const ushort4*)(z + (size_t)sB * 256 + lane * 4);
        ushort4 vC = *(const ushort4*)(z + (size_t)sC * 256 + lane * 4);
        ushort4 vD = *(const ushort4*)(z + (size_t)sD * 256 + lane * 4);
        a0 += bf2f(vA.x); a1 += bf2f(vA.y); a2 += bf2f(vA.z); a3 += bf2f(vA.w);
        b0 += bf2f(vB.x); b1 += bf2f(vB.y); b2 += bf2f(vB.z); b3 += bf2f(vB.w);
        c0 += bf2f(vC.x); c1 += bf2f(vC.y); c2 += bf2f(vC.z); c3 += bf2f(vC.w);
        d0 += bf2f(vD.x); d1 += bf2f(vD.y); d2 += bf2f(vD.z); d3 += bf2f(vD.w);
    }
    for (; e < deg; ++e) {
        int s = ep[e];
        ushort4 v = *(const ushort4*)(z + (size_t)s * 256 + lane * 4);
        a0 += bf2f(v.x); a1 += bf2f(v.y); a2 += bf2f(v.z); a3 += bf2f(v.w);
    }
    a0 += b0 + c0 + d0;
    a1 += b1 + c1 + d1;
    a2 += b2 + c2 + d2;
    a3 += b3 + c3 + d3;

    float post = rsqrtf((float)max(deg, 1));
    float4 bs = *(const float4*)(bias + lane * 4);
    float4 o;
    o.x = a0 * post + bs.x;
    o.y = a1 * post + bs.y;
    o.z = a2 * post + bs.z;
    o.w = a3 * post + bs.w;
    *(float4*)(out + (size_t)node * 256 + lane * 4) = o;
}

extern "C" void kernel_launch(void* const* d_in, const int* in_sizes, int n_in,
                              void* d_out, int out_size, void* d_ws, size_t ws_size,
                              hipStream_t stream) {
    const float* feat = (const float*)d_in[0];
    const int*   src  = (const int*)d_in[1];
    const int*   dst  = (const int*)d_in[2];
    const float* W    = (const float*)d_in[3];
    const float* bias = (const float*)d_in[4];
    float* out = (float*)d_out;

    const int D = 256;
    int N = in_sizes[0] / D;   // 100000
    int E = in_sizes[1];       // 1600000

    // workspace layout (256B aligned chunks), total ~59.3 MB
    char* ws = (char*)d_ws;
    size_t off = 0;
    auto alloc = [&](size_t bytes) -> void* {
        void* p = ws + off;
        off += (bytes + 255) & ~(size_t)255;
        return p;
    };
    int*            cnt    = (int*)alloc(((size_t)2 * N + 64) * sizeof(int)); // outc|inc|total
    int*            outc   = cnt;
    int*            inc    = cnt + N;
    int*            total  = cnt + 2 * N;
    int*            start  = (int*)alloc((size_t)N * sizeof(int));
    int*            cursor = (int*)alloc((size_t)N * sizeof(int));
    int*            eidx   = (int*)alloc((size_t)E * sizeof(int));
    unsigned short* h      = (unsigned short*)alloc((size_t)N * D * sizeof(unsigned short));
    unsigned short* WT     = (unsigned short*)alloc((size_t)D * D * sizeof(unsigned short));
    (void)ws_size;

    hipMemsetAsync(cnt, 0, ((size_t)2 * N + 64) * sizeof(int), stream);

    k_deg<<<1024, 256, 0, stream>>>(src, dst, E, outc, inc);
    k_off<<<(N + 255) / 256, 256, 0, stream>>>(inc, N, total, start, cursor);
    k_fill<<<1024, 256, 0, stream>>>(src, dst, E, cursor, eidx);
    k_wt<<<(D * D) / 256, 256, 0, stream>>>(W, WT);
    k_hb<<<(N + 3) / 4, 256, 0, stream>>>(feat, outc, N, h);
    k_gemm<<<(N / 16 + 3) / 4, 256, 0, stream>>>(h, WT, N);
    k_agg<<<(N + 3) / 4, 256, 0, stream>>>(h, start, inc, eidx, bias, N, out);
}

// Round 4
// 653.362 us; speedup vs baseline: 1.5261x; 1.0415x over previous
//
#include <hip/hip_runtime.h>
#include <hip/hip_bf16.h>
#include <stdint.h>

// GraphConv (GCN layer), N=100000, E=1.6M, D=256, f32 in/out.
// Pipeline (project-then-aggregate; aggregation is linear):
//   1. k_deg:  degree counts (int atomics, 1 thread/edge)
//   2. k_off:  CSR bucket bases via per-block LDS scan + atomic base (order-free)
//   3. k_fill: bucket src ids by dst via atomic cursor (1 thread/edge)
//   4. k_wt:   WT[n][k] = bf16(W[k][n])
//   5. k_gemm: z = bf16(feat*pre) @ W  (pre-scale + bf16 cvt fused into A-load),
//              z bf16 -> ws
//   6. k_agg:  out[n] = rsqrt(max(indeg,1)) * sum_{in-edges} z[src] + bias
//              (half-wave per edge: 16B/lane gather, 2 edges in flight)

using short8  = __attribute__((ext_vector_type(8))) short;
using floatx4 = __attribute__((ext_vector_type(4))) float;
using ushort8 = __attribute__((ext_vector_type(8))) unsigned short;

static __device__ __forceinline__ unsigned short f32_to_bf16(float f) {
    unsigned int u = __float_as_uint(f);
    u += 0x7FFFu + ((u >> 16) & 1u);   // round-to-nearest-even
    return (unsigned short)(u >> 16);
}
static __device__ __forceinline__ float bf2f(unsigned short u) {
    return __uint_as_float((unsigned int)u << 16);
}

__global__ void k_deg(const int* __restrict__ src, const int* __restrict__ dst,
                      int E, int* __restrict__ outc, int* __restrict__ inc) {
    int i = blockIdx.x * blockDim.x + threadIdx.x;
    if (i < E) {
        atomicAdd(&outc[src[i]], 1);
        atomicAdd(&inc[dst[i]], 1);
    }
}

// per-block exclusive scan + atomic global base -> cursor (bucket order across
// blocks arbitrary; only base[n] / base[n]+deg[n] consistency matters)
__global__ void k_off(const int* __restrict__ inc, int N, int* __restrict__ total,
                      int* __restrict__ cursor) {
    __shared__ int ss[256];
    __shared__ int sbase;
    int t = threadIdx.x;
    int i = blockIdx.x * 256 + t;
    int d = (i < N) ? inc[i] : 0;
    int v = d;
    ss[t] = v;
    __syncthreads();
    for (int off = 1; off < 256; off <<= 1) {
        int u = (t >= off) ? ss[t - off] : 0;
        __syncthreads();
        v += u;
        ss[t] = v;
        __syncthreads();
    }
    if (t == 255) sbase = atomicAdd(total, v);   // v = block sum
    __syncthreads();
    if (i < N) cursor[i] = sbase + (v - d);      // exclusive prefix
}

__global__ void k_fill(const int* __restrict__ src, const int* __restrict__ dst,
                       int E, int* __restrict__ cursor, int* __restrict__ eidx) {
    int i = blockIdx.x * blockDim.x + threadIdx.x;
    if (i < E) {
        int p = atomicAdd(&cursor[dst[i]], 1);
        eidx[p] = src[i];
    }
}

// WT[n*256+k] = bf16(W[k*256+n])
__global__ void k_wt(const float* __restrict__ W, unsigned short* __restrict__ WT) {
    int i = blockIdx.x * blockDim.x + threadIdx.x;   // 65536 threads
    int n = i >> 8, k = i & 255;
    WT[n * 256 + k] = f32_to_bf16(W[(size_t)k * 256 + n]);
}

// z = bf16(feat*pre) @ W, bf16 out. Per wave: 16 rows x 256 cols, K=256.
__global__ void __launch_bounds__(256)
k_gemm(const float* __restrict__ feat, const int* __restrict__ outc,
       const unsigned short* __restrict__ WT, int N,
       unsigned short* __restrict__ z) {
    int wave = blockIdx.x * 4 + (threadIdx.x >> 6);
    int m0 = wave * 16;
    if (m0 >= N) return;
    int lane = threadIdx.x & 63;
    int r = lane & 15;       // A row / B col within 16
    int g = lane >> 4;       // k-group 0..3

    int row = m0 + r;
    float p = rsqrtf((float)max(outc[row], 1));
    const float4* arow = (const float4*)(feat + (size_t)row * 256);

    floatx4 acc[16];
#pragma unroll
    for (int n = 0; n < 16; ++n) acc[n] = (floatx4){0.f, 0.f, 0.f, 0.f};

#pragma unroll
    for (int k = 0; k < 8; ++k) {
        // A fragment: feat f32 -> *pre -> bf16, k-cols k*32+g*8 .. +8
        float4 v0 = arow[k * 8 + g * 2];
        float4 v1 = arow[k * 8 + g * 2 + 1];
        short8 a;
        a[0] = (short)f32_to_bf16(v0.x * p);
        a[1] = (short)f32_to_bf16(v0.y * p);
        a[2] = (short)f32_to_bf16(v0.z * p);
        a[3] = (short)f32_to_bf16(v0.w * p);
        a[4] = (short)f32_to_bf16(v1.x * p);
        a[5] = (short)f32_to_bf16(v1.y * p);
        a[6] = (short)f32_to_bf16(v1.z * p);
        a[7] = (short)f32_to_bf16(v1.w * p);
#pragma unroll
        for (int n = 0; n < 16; ++n) {
            short8 b = *(const short8*)(WT + (size_t)(n * 16 + r) * 256 + k * 32 + g * 8);
            acc[n] = __builtin_amdgcn_mfma_f32_16x16x32_bf16(a, b, acc[n], 0, 0, 0);
        }
    }

#pragma unroll
    for (int n = 0; n < 16; ++n) {
        int c = n * 16 + r;
#pragma unroll
        for (int i = 0; i < 4; ++i) {
            int rw = m0 + g * 4 + i;
            z[(size_t)rw * 256 + c] = f32_to_bf16(acc[n][i]);
        }
    }
}

// out[n] = rsqrt(max(deg,1)) * sum z[src] + bias; one wave per dst node.
// Half-wave per edge: lane l of half h reads 16B (8 cols) of edge e+h.
__global__ void k_agg(const unsigned short* __restrict__ z,
                      const int* __restrict__ cursor, const int* __restrict__ inc,
                      const int* __restrict__ eidx, const float* __restrict__ bias,
                      int N, float* __restrict__ out) {
    int node = blockIdx.x * 4 + (threadIdx.x >> 6);
    if (node >= N) return;
    int lane = threadIdx.x & 63;
    int half = lane >> 5;
    int l = lane & 31;
    int deg = inc[node];
    const int* ep = eidx + (cursor[node] - deg);   // cursor is END after k_fill

    float acc[8];
#pragma unroll
    for (int j = 0; j < 8; ++j) acc[j] = 0.f;

    int e = 0;
    for (; e + 1 < deg; e += 2) {
        int s = ep[e + half];
        ushort8 v = *(const ushort8*)(z + (size_t)s * 256 + l * 8);
#pragma unroll
        for (int j = 0; j < 8; ++j) acc[j] += bf2f(v[j]);
    }
    if (e < deg && half == 0) {       // odd tail: half 0 only
        int s = ep[e];
        ushort8 v = *(const ushort8*)(z + (size_t)s * 256 + l * 8);
#pragma unroll
        for (int j = 0; j < 8; ++j) acc[j] += bf2f(v[j]);
    }
    // combine halves: lane l and l+32 hold the same 8 cols
#pragma unroll
    for (int j = 0; j < 8; ++j) acc[j] += __shfl_xor(acc[j], 32);

    float post = rsqrtf((float)max(deg, 1));
    // full-wave write: half 0 writes cols l*8..+4, half 1 cols l*8+4..+8
    int c0 = l * 8 + half * 4;
    float4 bs = *(const float4*)(bias + c0);
    float4 o;
    o.x = acc[half * 4 + 0] * post + bs.x;
    o.y = acc[half * 4 + 1] * post + bs.y;
    o.z = acc[half * 4 + 2] * post + bs.z;
    o.w = acc[half * 4 + 3] * post + bs.w;
    *(float4*)(out + (size_t)node * 256 + c0) = o;
}

extern "C" void kernel_launch(void* const* d_in, const int* in_sizes, int n_in,
                              void* d_out, int out_size, void* d_ws, size_t ws_size,
                              hipStream_t stream) {
    const float* feat = (const float*)d_in[0];
    const int*   src  = (const int*)d_in[1];
    const int*   dst  = (const int*)d_in[2];
    const float* W    = (const float*)d_in[3];
    const float* bias = (const float*)d_in[4];
    float* out = (float*)d_out;

    const int D = 256;
    int N = in_sizes[0] / D;   // 100000
    int E = in_sizes[1];       // 1600000

    // workspace layout (256B aligned chunks), total ~58 MB
    char* ws = (char*)d_ws;
    size_t off = 0;
    auto alloc = [&](size_t bytes) -> void* {
        void* p = ws + off;
        off += (bytes + 255) & ~(size_t)255;
        return p;
    };
    int*            cnt    = (int*)alloc(((size_t)2 * N + 64) * sizeof(int)); // outc|inc|total
    int*            outc   = cnt;
    int*            inc    = cnt + N;
    int*            total  = cnt + 2 * N;
    int*            cursor = (int*)alloc((size_t)N * sizeof(int));
    int*            eidx   = (int*)alloc((size_t)E * sizeof(int));
    unsigned short* z      = (unsigned short*)alloc((size_t)N * D * sizeof(unsigned short));
    unsigned short* WT     = (unsigned short*)alloc((size_t)D * D * sizeof(unsigned short));
    (void)ws_size;

    hipMemsetAsync(cnt, 0, ((size_t)2 * N + 64) * sizeof(int), stream);

    k_deg <<<(E + 255) / 256, 256, 0, stream>>>(src, dst, E, outc, inc);
    k_off <<<(N + 255) / 256, 256, 0, stream>>>(inc, N, total, cursor);
    k_fill<<<(E + 255) / 256, 256, 0, stream>>>(src, dst, E, cursor, eidx);
    k_wt  <<<(D * D) / 256, 256, 0, stream>>>(W, WT);
    k_gemm<<<(N / 16 + 3) / 4, 256, 0, stream>>>(feat, outc, WT, N, z);
    k_agg <<<(N + 3) / 4, 256, 0, stream>>>(z, cursor, inc, eidx, bias, N, out);
}

// Round 5
// 566.813 us; speedup vs baseline: 1.7592x; 1.1527x over previous
//
#include <hip/hip_runtime.h>
#include <hip/hip_bf16.h>
#include <stdint.h>

// GraphConv (GCN layer), N=100000, E=1.6M, D=256, f32 in/out.
// Pipeline (project-then-aggregate; aggregation is linear):
//   1. k_deg:  degree counts (int atomics, 1 thread/edge)
//   2. k_off:  CSR bucket bases via per-block LDS scan + atomic base (order-free)
//   3. k_fill: bucket src ids by dst via atomic cursor (1 thread/edge)
//   4. k_wt:   WT[n][k] = bf16(W[k][n])
//   5. k_gemm: z = bf16(feat*pre) @ W, LDS-staged WT (2 K-halves, XOR-swizzled),
//              z stored COLUMN-PERMUTED: z[row][p] with p = r*16+n holds col n*16+r
//   6. k_agg:  out[n] = rsqrt(max(indeg,1)) * sum_{in-edges} z[src] + bias
//              (half-wave per edge, 16B/lane gather; de-permutes at final store)

using short8  = __attribute__((ext_vector_type(8))) short;
using floatx4 = __attribute__((ext_vector_type(4))) float;
using ushort8 = __attribute__((ext_vector_type(8))) unsigned short;

static __device__ __forceinline__ unsigned short f32_to_bf16(float f) {
    unsigned int u = __float_as_uint(f);
    u += 0x7FFFu + ((u >> 16) & 1u);   // round-to-nearest-even
    return (unsigned short)(u >> 16);
}
static __device__ __forceinline__ float bf2f(unsigned short u) {
    return __uint_as_float((unsigned int)u << 16);
}

__global__ void k_deg(const int* __restrict__ src, const int* __restrict__ dst,
                      int E, int* __restrict__ outc, int* __restrict__ inc) {
    int i = blockIdx.x * blockDim.x + threadIdx.x;
    if (i < E) {
        atomicAdd(&outc[src[i]], 1);
        atomicAdd(&inc[dst[i]], 1);
    }
}

// per-block exclusive scan + atomic global base -> cursor (bucket order across
// blocks arbitrary; only base[n] / base[n]+deg[n] consistency matters)
__global__ void k_off(const int* __restrict__ inc, int N, int* __restrict__ total,
                      int* __restrict__ cursor) {
    __shared__ int ss[256];
    __shared__ int sbase;
    int t = threadIdx.x;
    int i = blockIdx.x * 256 + t;
    int d = (i < N) ? inc[i] : 0;
    int v = d;
    ss[t] = v;
    __syncthreads();
    for (int off = 1; off < 256; off <<= 1) {
        int u = (t >= off) ? ss[t - off] : 0;
        __syncthreads();
        v += u;
        ss[t] = v;
        __syncthreads();
    }
    if (t == 255) sbase = atomicAdd(total, v);   // v = block sum
    __syncthreads();
    if (i < N) cursor[i] = sbase + (v - d);      // exclusive prefix
}

__global__ void k_fill(const int* __restrict__ src, const int* __restrict__ dst,
                       int E, int* __restrict__ cursor, int* __restrict__ eidx) {
    int i = blockIdx.x * blockDim.x + threadIdx.x;
    if (i < E) {
        int p = atomicAdd(&cursor[dst[i]], 1);
        eidx[p] = src[i];
    }
}

// WT[n*256+k] = bf16(W[k*256+n])
__global__ void k_wt(const float* __restrict__ W, unsigned short* __restrict__ WT) {
    int i = blockIdx.x * blockDim.x + threadIdx.x;   // 65536 threads
    int n = i >> 8, k = i & 255;
    WT[n * 256 + k] = f32_to_bf16(W[(size_t)k * 256 + n]);
}

// z = bf16(feat*pre) @ W. Block: 512 thr (8 waves) x 128 rows x 256 cols.
// WT staged in 64KB LDS per K-half, XOR-swizzled (byte ^= (row&7)<<4).
// z written column-permuted: z[row][p], p=r*16+n  <->  col c=(p&15)*16|(p>>4).
__global__ void __launch_bounds__(512, 4)
k_gemm(const float* __restrict__ feat, const int* __restrict__ outc,
       const unsigned short* __restrict__ WT, int N,
       unsigned short* __restrict__ z) {
    __shared__ unsigned short ldsB[256 * 128];   // [ncol 256][khalf 128] bf16, swizzled

    int tid  = threadIdx.x;
    int wave = tid >> 6;
    int lane = tid & 63;
    int rl   = lane & 15;        // A row / B col within 16
    int g    = lane >> 4;        // k-group 0..3
    int wm0  = blockIdx.x * 128 + wave * 16;
    int rowc = min(wm0 + rl, N - 1);
    float p  = rsqrtf((float)max(outc[rowc], 1));
    const float4* arow = (const float4*)(feat + (size_t)rowc * 256);
    int smask = (rl & 7) << 4;   // per-lane swizzle mask (n*16 preserves row&7)

    floatx4 acc[16];
#pragma unroll
    for (int n = 0; n < 16; ++n) acc[n] = (floatx4){0.f, 0.f, 0.f, 0.f};

#pragma unroll
    for (int h = 0; h < 2; ++h) {
        if (h) __syncthreads();          // phase-0 reads done before restage
        // stage: 4096 16B-chunks, 8 per thread, coalesced global -> swizzled LDS
#pragma unroll
        for (int i = 0; i < 8; ++i) {
            int c    = i * 512 + tid;
            int r2   = c >> 4;                  // n-row 0..255
            int colb = (c & 15) << 4;           // byte col 0..240
            ushort8 v = *(const ushort8*)(WT + r2 * 256 + h * 128 + (colb >> 1));
            int dst = r2 * 128 + ((colb ^ ((r2 & 7) << 4)) >> 1);
            *(ushort8*)(&ldsB[dst]) = v;
        }
        __syncthreads();

#pragma unroll
        for (int k2 = 0; k2 < 4; ++k2) {
            float4 v0 = arow[h * 32 + k2 * 8 + g * 2];
            float4 v1 = arow[h * 32 + k2 * 8 + g * 2 + 1];
            short8 a;
            a[0] = (short)f32_to_bf16(v0.x * p);
            a[1] = (short)f32_to_bf16(v0.y * p);
            a[2] = (short)f32_to_bf16(v0.z * p);
            a[3] = (short)f32_to_bf16(v0.w * p);
            a[4] = (short)f32_to_bf16(v1.x * p);
            a[5] = (short)f32_to_bf16(v1.y * p);
            a[6] = (short)f32_to_bf16(v1.z * p);
            a[7] = (short)f32_to_bf16(v1.w * p);
            int cb = (k2 * 64 + g * 16) ^ smask;    // swizzled byte col
#pragma unroll
            for (int n = 0; n < 16; ++n) {
                short8 b = *(const short8*)(&ldsB[(n * 16 + rl) * 128 + (cb >> 1)]);
                acc[n] = __builtin_amdgcn_mfma_f32_16x16x32_bf16(a, b, acc[n], 0, 0, 0);
            }
        }
    }

    // epilogue: lane (rl,g) holds rows wm0+g*4+i, cols n*16+rl.
    // store permuted: z[rw][p], p = rl*16+n -> two contiguous ushort8 per row.
#pragma unroll
    for (int i = 0; i < 4; ++i) {
        int rw = wm0 + g * 4 + i;
        if (rw < N) {
            ushort8 u0, u1;
#pragma unroll
            for (int j = 0; j < 8; ++j) {
                u0[j] = f32_to_bf16(acc[j][i]);
                u1[j] = f32_to_bf16(acc[8 + j][i]);
            }
            *(ushort8*)(z + (size_t)rw * 256 + rl * 16)     = u0;
            *(ushort8*)(z + (size_t)rw * 256 + rl * 16 + 8) = u1;
        }
    }
}

// out[n] = rsqrt(max(deg,1)) * sum z[src] + bias; one wave per dst node.
// Half-wave per edge: lane l of half h reads 16B (8 permuted cols) of edge e+h.
// De-permute at the final store: c = ((p&15)<<4) | (p>>4).
__global__ void k_agg(const unsigned short* __restrict__ z,
                      const int* __restrict__ cursor, const int* __restrict__ inc,
                      const int* __restrict__ eidx, const float* __restrict__ bias,
                      int N, float* __restrict__ out) {
    int node = blockIdx.x * 4 + (threadIdx.x >> 6);
    if (node >= N) return;
    int lane = threadIdx.x & 63;
    int half = lane >> 5;
    int l = lane & 31;
    int deg = inc[node];
    const int* ep = eidx + (cursor[node] - deg);   // cursor is END after k_fill

    float acc[8];
#pragma unroll
    for (int j = 0; j < 8; ++j) acc[j] = 0.f;

    int e = 0;
    for (; e + 1 < deg; e += 2) {
        int s = ep[e + half];
        ushort8 v = *(const ushort8*)(z + (size_t)s * 256 + l * 8);
#pragma unroll
        for (int j = 0; j < 8; ++j) acc[j] += bf2f(v[j]);
    }
    if (e < deg && half == 0) {       // odd tail: half 0 only
        int s = ep[e];
        ushort8 v = *(const ushort8*)(z + (size_t)s * 256 + l * 8);
#pragma unroll
        for (int j = 0; j < 8; ++j) acc[j] += bf2f(v[j]);
    }
    // combine halves: lane l and l+32 hold the same 8 permuted cols
#pragma unroll
    for (int j = 0; j < 8; ++j) acc[j] += __shfl_xor(acc[j], 32);

    float post = rsqrtf((float)max(deg, 1));
#pragma unroll
    for (int jj = 0; jj < 4; ++jj) {
        int pcol = l * 8 + half * 4 + jj;
        int c = ((pcol & 15) << 4) | (pcol >> 4);
        out[(size_t)node * 256 + c] = acc[half * 4 + jj] * post + bias[c];
    }
}

extern "C" void kernel_launch(void* const* d_in, const int* in_sizes, int n_in,
                              void* d_out, int out_size, void* d_ws, size_t ws_size,
                              hipStream_t stream) {
    const float* feat = (const float*)d_in[0];
    const int*   src  = (const int*)d_in[1];
    const int*   dst  = (const int*)d_in[2];
    const float* W    = (const float*)d_in[3];
    const float* bias = (const float*)d_in[4];
    float* out = (float*)d_out;

    const int D = 256;
    int N = in_sizes[0] / D;   // 100000
    int E = in_sizes[1];       // 1600000

    // workspace layout (256B aligned chunks), total ~58 MB
    char* ws = (char*)d_ws;
    size_t off = 0;
    auto alloc = [&](size_t bytes) -> void* {
        void* p = ws + off;
        off += (bytes + 255) & ~(size_t)255;
        return p;
    };
    int*            cnt    = (int*)alloc(((size_t)2 * N + 64) * sizeof(int)); // outc|inc|total
    int*            outc   = cnt;
    int*            inc    = cnt + N;
    int*            total  = cnt + 2 * N;
    int*            cursor = (int*)alloc((size_t)N * sizeof(int));
    int*            eidx   = (int*)alloc((size_t)E * sizeof(int));
    unsigned short* z      = (unsigned short*)alloc((size_t)N * D * sizeof(unsigned short));
    unsigned short* WT     = (unsigned short*)alloc((size_t)D * D * sizeof(unsigned short));
    (void)ws_size;

    hipMemsetAsync(cnt, 0, ((size_t)2 * N + 64) * sizeof(int), stream);

    k_deg <<<(E + 255) / 256, 256, 0, stream>>>(src, dst, E, outc, inc);
    k_off <<<(N + 255) / 256, 256, 0, stream>>>(inc, N, total, cursor);
    k_fill<<<(E + 255) / 256, 256, 0, stream>>>(src, dst, E, cursor, eidx);
    k_wt  <<<(D * D) / 256, 256, 0, stream>>>(W, WT);
    k_gemm<<<(N + 127) / 128, 512, 0, stream>>>(feat, outc, WT, N, z);
    k_agg <<<(N + 3) / 4, 256, 0, stream>>>(z, cursor, inc, eidx, bias, N, out);
}